// Round 13
// baseline (454.134 us; speedup 1.0000x reference)
//
#include <hip/hip_runtime.h>
#include <hip/hip_bf16.h>
#include <cstdint>

#define D_IN 128
#define DK 32
#define NH 8
#define HD 256   // NH*DK

typedef __attribute__((ext_vector_type(8))) short short8;
typedef __attribute__((ext_vector_type(4))) float f32x4;

__device__ inline float u2f(unsigned int u) {
  union { unsigned int i; float f; } c; c.i = u; return c.f;
}
__device__ inline short f2bf(float f) {
  union { float f; unsigned int i; } c; c.f = f;
  unsigned int u = c.i;
  u = u + 0x7FFFu + ((u >> 16) & 1u);  // RNE
  return (short)(u >> 16);
}

// ---------- prep B: Wcat[128][768] -> bf16 MFMA B-fragments ----------
__global__ __launch_bounds__(256) void prep_w_kernel(
    const float* __restrict__ WQ, const float* __restrict__ WK,
    const float* __restrict__ WV, short8* __restrict__ Bbuf) {
  int ct = blockIdx.x;  // 0..47
  int t = threadIdx.x;
  int kt = t >> 6, L = t & 63;
  int col = ct * 16 + (L & 15);
  int type = col >> 8;
  const float* W = (type == 0) ? WQ : (type == 1) ? WK : WV;
  int head = (col & 255) >> 5;
  int kk = col & 31;
  int k0 = kt * 32 + ((L >> 4) << 3);
  short8 o;
  #pragma unroll
  for (int r = 0; r < 8; r++)
    o[r] = f2bf(W[head * (D_IN * DK) + (k0 + r) * DK + kk]);
  Bbuf[(size_t)(ct * 4 + kt) * 64 + L] = o;
}

// ---------- MFMA GEMM: one block per 16-node tile; head-major Qh / KVh out ----------
// Qh[head][node][32] bf16 PRE-SCALED by 1/sqrt(32)*log2(e) (so attn uses exp2).
// KVh[head][node][64] bf16 (128B rows: K32|V32).
__global__ __launch_bounds__(256) void gemm_qkv_kernel(
    const float* __restrict__ h, const short8* __restrict__ Bbuf,
    __hip_bfloat16* __restrict__ Qh, __hip_bfloat16* __restrict__ KVh,
    int nt_total, int n_node) {
  __shared__ float hs[16][132];
  __shared__ short lds[16][768];  // Q 0-255 | K 256-511 | V 512-767 (head-major in each)
  int nt = blockIdx.x;
  int t = threadIdx.x;
  {
    const float4* h4 = (const float4*)(h + (size_t)nt * 16 * 128);
    float4 v0 = h4[t * 2], v1 = h4[t * 2 + 1];
    int node = t >> 4, dim = (t & 15) * 8;
    hs[node][dim + 0] = v0.x; hs[node][dim + 1] = v0.y;
    hs[node][dim + 2] = v0.z; hs[node][dim + 3] = v0.w;
    hs[node][dim + 4] = v1.x; hs[node][dim + 5] = v1.y;
    hs[node][dim + 6] = v1.z; hs[node][dim + 7] = v1.w;
  }
  __syncthreads();
  int w = t >> 6;
  int L = t & 63;
  int arow = L & 15, k0base = ((L >> 4) << 3);
  short8 afrag[4];
  #pragma unroll
  for (int kt = 0; kt < 4; kt++) {
    #pragma unroll
    for (int r = 0; r < 8; r++)
      afrag[kt][r] = f2bf(hs[arow][kt * 32 + k0base + r]);
  }
  f32x4 acc[12];
  #pragma unroll
  for (int c = 0; c < 12; c++) acc[c] = (f32x4){0.f, 0.f, 0.f, 0.f};
  #pragma unroll
  for (int kt = 0; kt < 4; kt++) {
    #pragma unroll
    for (int c = 0; c < 12; c++) {
      short8 b = Bbuf[(size_t)((w * 12 + c) * 4 + kt) * 64 + L];
      acc[c] = __builtin_amdgcn_mfma_f32_16x16x32_bf16(afrag[kt], b, acc[c], 0, 0, 0);
    }
  }
  int row0 = (L >> 4) << 2;
  int col0 = w * 192 + (L & 15);
  const float QSL = 0.25506966f;  // (1/sqrt(32)) * log2(e)
  #pragma unroll
  for (int c = 0; c < 12; c++) {
    float sc = ((w * 192 + c * 16) < 256) ? QSL : 1.f;  // Q cols pre-scaled
    #pragma unroll
    for (int r = 0; r < 4; r++)
      lds[row0 + r][col0 + c * 16] = f2bf(acc[c][r] * sc);
  }
  __syncthreads();
  // Qh out: 512 16B-units. u: head=u>>6, node=(u>>2)&15, part=u&3
  #pragma unroll
  for (int j = 0; j < 2; j++) {
    int u = t + j * 256;
    int hh = u >> 6, r2 = (u >> 2) & 15, part = u & 3;
    float4 vdat = *(const float4*)&lds[r2][hh * 32 + part * 8];
    *(float4*)(Qh + ((size_t)hh * n_node + nt * 16 + r2) * 32 + part * 8) = vdat;
  }
  // KVh out: 1024 16B-units. u: head=u>>7, node=(u>>3)&15, part=u&7
  #pragma unroll
  for (int j = 0; j < 4; j++) {
    int u = t + j * 256;
    int hh = u >> 7, r2 = (u >> 3) & 15, part = u & 7;
    int srccol = (part < 4) ? (256 + hh * 32 + part * 8)
                            : (512 + hh * 32 + (part - 4) * 8);
    float4 vdat = *(const float4*)&lds[r2][srccol];
    *(float4*)(KVh + ((size_t)hh * n_node + nt * 16 + r2) * 64 +
               ((part < 4) ? part * 8 : 32 + (part - 4) * 8)) = vdat;
  }
}

// ---------------- CSR build ----------------
__global__ void rank_kernel(const int* __restrict__ row, int n_edge,
                            int* __restrict__ cnt, int* __restrict__ rank) {
  int i = blockIdx.x * blockDim.x + threadIdx.x;
  if (i < n_edge) rank[i] = atomicAdd(&cnt[row[i]], 1);
}

__global__ __launch_bounds__(256) void scan1_kernel(
    const int* __restrict__ cnt, int n, int* __restrict__ exc,
    int* __restrict__ bsum) {
  __shared__ int s[256];
  int gid = blockIdx.x * 256 + threadIdx.x;
  int v = (gid < n) ? cnt[gid] : 0;
  s[threadIdx.x] = v;
  __syncthreads();
  #pragma unroll
  for (int off = 1; off < 256; off <<= 1) {
    int t = (threadIdx.x >= off) ? s[threadIdx.x - off] : 0;
    __syncthreads();
    s[threadIdx.x] += t;
    __syncthreads();
  }
  if (gid < n) exc[gid] = s[threadIdx.x] - v;
  if (threadIdx.x == 255) bsum[blockIdx.x] = s[255];
}

__global__ __launch_bounds__(256) void scan2_kernel(int* __restrict__ bsum,
                                                    int nb) {
  __shared__ int s[256];
  int v = (threadIdx.x < nb) ? bsum[threadIdx.x] : 0;
  s[threadIdx.x] = v;
  __syncthreads();
  #pragma unroll
  for (int off = 1; off < 256; off <<= 1) {
    int t = (threadIdx.x >= off) ? s[threadIdx.x - off] : 0;
    __syncthreads();
    s[threadIdx.x] += t;
    __syncthreads();
  }
  if (threadIdx.x < nb) bsum[threadIdx.x] = s[threadIdx.x] - v;
}

__global__ __launch_bounds__(256) void scan3_kernel(
    int* __restrict__ exc, const int* __restrict__ bsum, int n, int n_edge) {
  int gid = blockIdx.x * 256 + threadIdx.x;
  if (gid < n) exc[gid] = exc[gid] + bsum[blockIdx.x];
  if (gid == 0) exc[n] = n_edge;
}

__global__ void scatter_kernel(const int* __restrict__ row,
                               const int* __restrict__ col,
                               const int* __restrict__ rank, int n_edge,
                               const int* __restrict__ offsets,
                               int* __restrict__ col_sorted) {
  int i = blockIdx.x * blockDim.x + threadIdx.x;
  if (i < n_edge) col_sorted[offsets[row[i]] + rank[i]] = col[i];
}

// ---------------- Attention: head-partitioned + MFMA dot, no in-loop shfl ----------------
// head = blockIdx%8 (XCD-pinned slice, FETCH-halving proven r11/r12).
// Wave = (node, head); 16 edges per chunk.
//   K-frag (MFMA A): lane L = edge (L&15), dims (L>>4)*8.. (verified layout)
//   B = q replicated in all 16 cols (q pre-scaled by 1/sqrt(32)*log2e at GEMM)
//   D: lane's 4 regs = logits of edges 4*(L>>4)+r  ->  p_r = exp2f(D[r])
//   V edge for lane = 4*(L>>4)+(L&3)  ->  needed p is a LANE-LOCAL register
//   select (3 cndmask, zero shfl). V dims chunk = (L>>2)&3.
// All cross-lane reduction deferred to a once-per-node epilogue.
__global__ __launch_bounds__(256) void attn_kernel(
    const __hip_bfloat16* __restrict__ Qh, const __hip_bfloat16* __restrict__ KVh,
    const int* __restrict__ offsets, const int* __restrict__ col_sorted,
    float* __restrict__ out, int n_node) {
  int head = blockIdx.x & 7;   // XCD-pinned
  int grp = blockIdx.x >> 3;
  int wv = threadIdx.x >> 6;
  int lane = threadIdx.x & 63;
  int node = grp * 4 + wv;
  if (node >= n_node) return;
  int start = offsets[node], end = offsets[node + 1];

  int kc = lane >> 4;           // K dim-chunk / logit group
  int erow = lane & 15;         // K-frag edge row
  int vc = lane & 3;            // p-register selector
  int vchunk = (lane >> 2) & 3; // V dim-chunk
  int vslot = (kc << 2) | vc;   // V edge slot = 4*kc + vc

  if (end <= start) {
    if (vc == 0 && kc == 0) {   // lanes 0,4,8,12
      float* op = out + (size_t)node * HD + head * 32 + vchunk * 8;
      float4 z = make_float4(0.f, 0.f, 0.f, 0.f);
      *(float4*)op = z;
      *(float4*)(op + 4) = z;
    }
    return;
  }

  // B-fragment: q chunk kc (8 bf16, already scaled); identical for all erow.
  short8 qb = *(const short8*)(Qh + ((size_t)head * n_node + node) * 32 + kc * 8);

  float dn = 0.f;
  float a0 = 0.f, a1 = 0.f, a2 = 0.f, a3 = 0.f;
  float a4 = 0.f, a5 = 0.f, a6 = 0.f, a7 = 0.f;
  const char* kvb = (const char*)KVh + (size_t)head * n_node * 128;

  for (int base = start; base < end; base += 16) {
    int iK = base + erow;
    int iV = base + vslot;
    int cK = col_sorted[iK < end ? iK : start];
    int cV = col_sorted[iV < end ? iV : start];
    short8 kf = *(const short8*)(kvb + (size_t)cK * 128 + kc * 16);
    uint4 vf = *(const uint4*)(kvb + (size_t)cV * 128 + 64 + vchunk * 16);
    f32x4 dm = __builtin_amdgcn_mfma_f32_16x16x32_bf16(
        kf, qb, (f32x4){0.f, 0.f, 0.f, 0.f}, 0, 0, 0);
    int e0 = base + (kc << 2);
    float p0 = (e0 < end) ? exp2f(dm[0]) : 0.f;
    float p1 = (e0 + 1 < end) ? exp2f(dm[1]) : 0.f;
    float p2 = (e0 + 2 < end) ? exp2f(dm[2]) : 0.f;
    float p3 = (e0 + 3 < end) ? exp2f(dm[3]) : 0.f;
    dn += (p0 + p1) + (p2 + p3);
    float pb = (vc == 0) ? p0 : (vc == 1) ? p1 : (vc == 2) ? p2 : p3;
    a0 = fmaf(pb, u2f(vf.x << 16), a0);
    a1 = fmaf(pb, u2f(vf.x & 0xFFFF0000u), a1);
    a2 = fmaf(pb, u2f(vf.y << 16), a2);
    a3 = fmaf(pb, u2f(vf.y & 0xFFFF0000u), a3);
    a4 = fmaf(pb, u2f(vf.z << 16), a4);
    a5 = fmaf(pb, u2f(vf.z & 0xFFFF0000u), a5);
    a6 = fmaf(pb, u2f(vf.w << 16), a6);
    a7 = fmaf(pb, u2f(vf.w & 0xFFFF0000u), a7);
  }

  // epilogue reduce: accs over lane bits 0,1 (vc) and 4,5 (kc); dn over 4,5
#define RED4(x)                                                              \
  x += __shfl_xor(x, 1); x += __shfl_xor(x, 2);                              \
  x += __shfl_xor(x, 16); x += __shfl_xor(x, 32);
  RED4(a0) RED4(a1) RED4(a2) RED4(a3) RED4(a4) RED4(a5) RED4(a6) RED4(a7)
  dn += __shfl_xor(dn, 16);
  dn += __shfl_xor(dn, 32);
  float inv = 1.f / dn;
  if (vc == 0 && kc == 0) {  // lanes 0,4,8,12: dims vchunk*8..+7
    float* op = out + (size_t)node * HD + head * 32 + vchunk * 8;
    float4 o0 = make_float4(a0 * inv, a1 * inv, a2 * inv, a3 * inv);
    float4 o1 = make_float4(a4 * inv, a5 * inv, a6 * inv, a7 * inv);
    *(float4*)op = o0;
    *(float4*)(op + 4) = o1;
  }
}

extern "C" void kernel_launch(void* const* d_in, const int* in_sizes, int n_in,
                              void* d_out, int out_size, void* d_ws,
                              size_t ws_size, hipStream_t stream) {
  const float* h = (const float*)d_in[0];
  const int* edge = (const int*)d_in[1];
  const float* WQ = (const float*)d_in[2];
  const float* WK = (const float*)d_in[3];
  const float* WV = (const float*)d_in[4];
  float* out = (float*)d_out;

  int n_node = in_sizes[0] / D_IN;
  int n_edge = in_sizes[1] / 2;
  const int* row = edge;
  const int* col = edge + n_edge;

  char* ws = (char*)d_ws;
  size_t off = 0;
  auto alloc = [&](size_t bytes) {
    void* p = ws + off;
    off += (bytes + 255) & ~(size_t)255;
    return p;
  };
  int nt_total = (n_node + 15) / 16;  // 3125 (50000 = 3125*16 exactly)
  __hip_bfloat16* Qh = (__hip_bfloat16*)alloc((size_t)NH * n_node * 32 * 2);
  __hip_bfloat16* KVh = (__hip_bfloat16*)alloc((size_t)NH * n_node * 64 * 2);
  short8* Bbuf = (short8*)alloc((size_t)48 * 4 * 64 * 16);
  int* col_sorted = (int*)alloc((size_t)n_edge * 4);
  int* rank = (int*)alloc((size_t)n_edge * 4);
  int* cnt = (int*)alloc((size_t)n_node * 4);
  int* offsets = (int*)alloc((size_t)(n_node + 1) * 4);
  int* bsum = (int*)alloc(256 * 4);

  hipMemsetAsync(cnt, 0, (size_t)n_node * 4, stream);

  prep_w_kernel<<<48, 256, 0, stream>>>(WQ, WK, WV, Bbuf);
  gemm_qkv_kernel<<<nt_total, 256, 0, stream>>>(h, Bbuf, Qh, KVh, nt_total,
                                                n_node);

  int nb_e = (n_edge + 255) / 256;
  rank_kernel<<<nb_e, 256, 0, stream>>>(row, n_edge, cnt, rank);

  int nb = (n_node + 255) / 256;
  scan1_kernel<<<nb, 256, 0, stream>>>(cnt, n_node, offsets, bsum);
  scan2_kernel<<<1, 256, 0, stream>>>(bsum, nb);
  scan3_kernel<<<nb, 256, 0, stream>>>(offsets, bsum, n_node, n_edge);

  scatter_kernel<<<nb_e, 256, 0, stream>>>(row, col, rank, n_edge, offsets,
                                           col_sorted);

  attn_kernel<<<((n_node + 3) / 4) * 8, 256, 0, stream>>>(
      Qh, KVh, offsets, col_sorted, out, n_node);
}

// Round 14
// 376.731 us; speedup vs baseline: 1.2055x; 1.2055x over previous
//
#include <hip/hip_runtime.h>
#include <hip/hip_bf16.h>
#include <cstdint>

#define D_IN 128
#define DK 32
#define NH 8
#define HD 256   // NH*DK

typedef __attribute__((ext_vector_type(8))) short short8;
typedef __attribute__((ext_vector_type(4))) float f32x4;

__device__ inline float u2f(unsigned int u) {
  union { unsigned int i; float f; } c; c.i = u; return c.f;
}
__device__ inline short f2bf(float f) {
  union { float f; unsigned int i; } c; c.f = f;
  unsigned int u = c.i;
  u = u + 0x7FFFu + ((u >> 16) & 1u);  // RNE
  return (short)(u >> 16);
}

// ---------- prep B: Wcat[128][768] -> bf16 MFMA B-fragments ----------
__global__ __launch_bounds__(256) void prep_w_kernel(
    const float* __restrict__ WQ, const float* __restrict__ WK,
    const float* __restrict__ WV, short8* __restrict__ Bbuf) {
  int ct = blockIdx.x;  // 0..47
  int t = threadIdx.x;
  int kt = t >> 6, L = t & 63;
  int col = ct * 16 + (L & 15);
  int type = col >> 8;
  const float* W = (type == 0) ? WQ : (type == 1) ? WK : WV;
  int head = (col & 255) >> 5;
  int kk = col & 31;
  int k0 = kt * 32 + ((L >> 4) << 3);
  short8 o;
  #pragma unroll
  for (int r = 0; r < 8; r++)
    o[r] = f2bf(W[head * (D_IN * DK) + (k0 + r) * DK + kk]);
  Bbuf[(size_t)(ct * 4 + kt) * 64 + L] = o;
}

// ---------- MFMA GEMM: head-major Qh (PRE-SCALED by 1/sqrt(32)*log2e) + KVh ----------
// Qh[head][node][32]; KVh[head][node][64] with n_node+1 rows/head (last = sentinel).
__global__ __launch_bounds__(256) void gemm_qkv_kernel(
    const float* __restrict__ h, const short8* __restrict__ Bbuf,
    __hip_bfloat16* __restrict__ Qh, __hip_bfloat16* __restrict__ KVh,
    int nt_total, int n_node) {
  __shared__ float hs[16][132];
  __shared__ short lds[16][768];  // Q 0-255 | K 256-511 | V 512-767 (head-major)
  int nt = blockIdx.x;
  int t = threadIdx.x;
  {
    const float4* h4 = (const float4*)(h + (size_t)nt * 16 * 128);
    float4 v0 = h4[t * 2], v1 = h4[t * 2 + 1];
    int node = t >> 4, dim = (t & 15) * 8;
    hs[node][dim + 0] = v0.x; hs[node][dim + 1] = v0.y;
    hs[node][dim + 2] = v0.z; hs[node][dim + 3] = v0.w;
    hs[node][dim + 4] = v1.x; hs[node][dim + 5] = v1.y;
    hs[node][dim + 6] = v1.z; hs[node][dim + 7] = v1.w;
  }
  __syncthreads();
  int w = t >> 6;
  int L = t & 63;
  int arow = L & 15, k0base = ((L >> 4) << 3);
  short8 afrag[4];
  #pragma unroll
  for (int kt = 0; kt < 4; kt++) {
    #pragma unroll
    for (int r = 0; r < 8; r++)
      afrag[kt][r] = f2bf(hs[arow][kt * 32 + k0base + r]);
  }
  f32x4 acc[12];
  #pragma unroll
  for (int c = 0; c < 12; c++) acc[c] = (f32x4){0.f, 0.f, 0.f, 0.f};
  #pragma unroll
  for (int kt = 0; kt < 4; kt++) {
    #pragma unroll
    for (int c = 0; c < 12; c++) {
      short8 b = Bbuf[(size_t)((w * 12 + c) * 4 + kt) * 64 + L];
      acc[c] = __builtin_amdgcn_mfma_f32_16x16x32_bf16(afrag[kt], b, acc[c], 0, 0, 0);
    }
  }
  int row0 = (L >> 4) << 2;
  int col0 = w * 192 + (L & 15);
  const float QSL = 0.25506966f;  // (1/sqrt(32)) * log2(e)
  #pragma unroll
  for (int c = 0; c < 12; c++) {
    float sc = ((w * 192 + c * 16) < 256) ? QSL : 1.f;  // Q cols pre-scaled
    #pragma unroll
    for (int r = 0; r < 4; r++)
      lds[row0 + r][col0 + c * 16] = f2bf(acc[c][r] * sc);
  }
  __syncthreads();
  // Qh out
  #pragma unroll
  for (int j = 0; j < 2; j++) {
    int u = t + j * 256;
    int hh = u >> 6, r2 = (u >> 2) & 15, part = u & 3;
    float4 vdat = *(const float4*)&lds[r2][hh * 32 + part * 8];
    *(float4*)(Qh + ((size_t)hh * n_node + nt * 16 + r2) * 32 + part * 8) = vdat;
  }
  // KVh out (stride n_node+1 rows per head)
  #pragma unroll
  for (int j = 0; j < 4; j++) {
    int u = t + j * 256;
    int hh = u >> 7, r2 = (u >> 3) & 15, part = u & 7;
    int srccol = (part < 4) ? (256 + hh * 32 + part * 8)
                            : (512 + hh * 32 + (part - 4) * 8);
    float4 vdat = *(const float4*)&lds[r2][srccol];
    *(float4*)(KVh + ((size_t)hh * (n_node + 1) + nt * 16 + r2) * 64 +
               ((part < 4) ? part * 8 : 32 + (part - 4) * 8)) = vdat;
  }
}

// ---------- fill: col_sorted <- sentinel; zero the 8 sentinel KV rows ----------
__global__ void fill_kernel(int* __restrict__ col_sorted, int cap,
                            __hip_bfloat16* __restrict__ KVh, int n_node) {
  int i = blockIdx.x * 256 + threadIdx.x;
  if (i < cap) col_sorted[i] = n_node;  // sentinel index
  if (i < 512) {
    int hh = i >> 6, j = i & 63;
    KVh[((size_t)hh * (n_node + 1) + n_node) * 64 + j] = __float2bfloat16(0.f);
  }
}

// ---------------- CSR build ----------------
__global__ void rank_kernel(const int* __restrict__ row, int n_edge,
                            int* __restrict__ cnt, int* __restrict__ rank) {
  int i = blockIdx.x * blockDim.x + threadIdx.x;
  if (i < n_edge) rank[i] = atomicAdd(&cnt[row[i]], 1);
}

// scan over PADDED counts: ceil16(cnt)
__global__ __launch_bounds__(256) void scan1_kernel(
    const int* __restrict__ cnt, int n, int* __restrict__ exc,
    int* __restrict__ bsum) {
  __shared__ int s[256];
  int gid = blockIdx.x * 256 + threadIdx.x;
  int v = (gid < n) ? ((cnt[gid] + 15) & ~15) : 0;
  s[threadIdx.x] = v;
  __syncthreads();
  #pragma unroll
  for (int off = 1; off < 256; off <<= 1) {
    int t = (threadIdx.x >= off) ? s[threadIdx.x - off] : 0;
    __syncthreads();
    s[threadIdx.x] += t;
    __syncthreads();
  }
  if (gid < n) exc[gid] = s[threadIdx.x] - v;
  if (threadIdx.x == 255) bsum[blockIdx.x] = s[255];
}

__global__ __launch_bounds__(256) void scan2_kernel(int* __restrict__ bsum,
                                                    int nb) {
  __shared__ int s[256];
  int v = (threadIdx.x < nb) ? bsum[threadIdx.x] : 0;
  s[threadIdx.x] = v;
  __syncthreads();
  #pragma unroll
  for (int off = 1; off < 256; off <<= 1) {
    int t = (threadIdx.x >= off) ? s[threadIdx.x - off] : 0;
    __syncthreads();
    s[threadIdx.x] += t;
    __syncthreads();
  }
  if (threadIdx.x < nb) bsum[threadIdx.x] = s[threadIdx.x] - v;
}

__global__ __launch_bounds__(256) void scan3_kernel(
    int* __restrict__ exc, const int* __restrict__ bsum,
    const int* __restrict__ cnt, int n) {
  int gid = blockIdx.x * 256 + threadIdx.x;
  if (gid < n) {
    int o = exc[gid] + bsum[blockIdx.x];
    exc[gid] = o;
    if (gid == n - 1) exc[n] = o + ((cnt[gid] + 15) & ~15);
  }
}

__global__ void scatter_kernel(const int* __restrict__ row,
                               const int* __restrict__ col,
                               const int* __restrict__ rank, int n_edge,
                               const int* __restrict__ offsets,
                               int* __restrict__ col_sorted) {
  int i = blockIdx.x * blockDim.x + threadIdx.x;
  if (i < n_edge) col_sorted[offsets[row[i]] + rank[i]] = col[i];
}

// ---------------- Attention: head-partitioned, branchless padded loop ----------------
// head = blockIdx%8 (XCD-pinned 6.4MB slice; FETCH-halving proven r11/r12).
// Edge lists padded to x16 with sentinel (zero KV row): pad edge contributes
// exactly exp2(0)=1 to denom, 0 to numerator -> subtract pad count once.
// Lane l: g=l>>3 edge slot, s=l&7 (0-3: K dims 8s.., 4-7: V dims 8(s-4)..).
// Qh pre-scaled -> p = exp2f(logit), no mul.
#define PROC(r)                                                              \
  {                                                                          \
    float x0 = u2f(r.x << 16), x1 = u2f(r.x & 0xFFFF0000u);                  \
    float x2 = u2f(r.y << 16), x3 = u2f(r.y & 0xFFFF0000u);                  \
    float x4 = u2f(r.z << 16), x5 = u2f(r.z & 0xFFFF0000u);                  \
    float x6 = u2f(r.w << 16), x7 = u2f(r.w & 0xFFFF0000u);                  \
    float d = x0 * qf0;                                                      \
    d = fmaf(x1, qf1, d); d = fmaf(x2, qf2, d); d = fmaf(x3, qf3, d);        \
    d = fmaf(x4, qf4, d); d = fmaf(x5, qf5, d); d = fmaf(x6, qf6, d);        \
    d = fmaf(x7, qf7, d);                                                    \
    d += __shfl_xor(d, 1);                                                   \
    d += __shfl_xor(d, 2);                                                   \
    float tt = __shfl_xor(d, 4);                                             \
    float lg = (s < 4) ? d : tt;                                             \
    float p = exp2f(lg);                                                     \
    dn += p;                                                                 \
    a0 = fmaf(p, x0, a0); a1 = fmaf(p, x1, a1);                              \
    a2 = fmaf(p, x2, a2); a3 = fmaf(p, x3, a3);                              \
    a4 = fmaf(p, x4, a4); a5 = fmaf(p, x5, a5);                              \
    a6 = fmaf(p, x6, a6); a7 = fmaf(p, x7, a7);                              \
  }

__global__ __launch_bounds__(256) void attn_kernel(
    const __hip_bfloat16* __restrict__ Qh, const __hip_bfloat16* __restrict__ KVh,
    const int* __restrict__ offsets, const int* __restrict__ cnt,
    const int* __restrict__ col_sorted, float* __restrict__ out, int n_node) {
  int head = blockIdx.x & 7;   // XCD-pinned
  int grp = blockIdx.x >> 3;
  int wv = threadIdx.x >> 6;
  int lane = threadIdx.x & 63;
  int g = lane >> 3;  // edge slot 0..7
  int s = lane & 7;   // 0-3: K dims 8s..; 4-7: V dims 8(s-4)..
  int node = grp * 4 + wv;
  if (node >= n_node) return;
  int start = offsets[node], end = offsets[node + 1];

  if (end <= start) {
    if (g == 0 && s >= 4) {
      float* op = out + (size_t)node * HD + head * 32 + (s - 4) * 8;
      float4 z = make_float4(0.f, 0.f, 0.f, 0.f);
      *(float4*)op = z;
      *(float4*)(op + 4) = z;
    }
    return;
  }

  float qf0, qf1, qf2, qf3, qf4, qf5, qf6, qf7;
  {
    uint4 qr = *(const uint4*)((const char*)(Qh +
                ((size_t)head * n_node + node) * 32) + (s & 3) * 16);
    qf0 = u2f(qr.x << 16); qf1 = u2f(qr.x & 0xFFFF0000u);
    qf2 = u2f(qr.y << 16); qf3 = u2f(qr.y & 0xFFFF0000u);
    qf4 = u2f(qr.z << 16); qf5 = u2f(qr.z & 0xFFFF0000u);
    qf6 = u2f(qr.w << 16); qf7 = u2f(qr.w & 0xFFFF0000u);
  }
  float dn = 0.f;
  float a0 = 0.f, a1 = 0.f, a2 = 0.f, a3 = 0.f;
  float a4 = 0.f, a5 = 0.f, a6 = 0.f, a7 = 0.f;

  const char* kvb = (const char*)KVh + (size_t)head * (n_node + 1) * 128 + s * 16;

  for (int base = start; base < end; base += 16) {
    int c0 = col_sorted[base + g];
    int c1 = col_sorted[base + 8 + g];
    uint4 r0 = *(const uint4*)(kvb + (size_t)c0 * 128);
    uint4 r1 = *(const uint4*)(kvb + (size_t)c1 * 128);
    PROC(r0);
    PROC(r1);
  }

  // merge the 8 edge-groups (xor over lane bits 3..5)
  dn += __shfl_xor(dn, 8); dn += __shfl_xor(dn, 16); dn += __shfl_xor(dn, 32);
  a0 += __shfl_xor(a0, 8); a0 += __shfl_xor(a0, 16); a0 += __shfl_xor(a0, 32);
  a1 += __shfl_xor(a1, 8); a1 += __shfl_xor(a1, 16); a1 += __shfl_xor(a1, 32);
  a2 += __shfl_xor(a2, 8); a2 += __shfl_xor(a2, 16); a2 += __shfl_xor(a2, 32);
  a3 += __shfl_xor(a3, 8); a3 += __shfl_xor(a3, 16); a3 += __shfl_xor(a3, 32);
  a4 += __shfl_xor(a4, 8); a4 += __shfl_xor(a4, 16); a4 += __shfl_xor(a4, 32);
  a5 += __shfl_xor(a5, 8); a5 += __shfl_xor(a5, 16); a5 += __shfl_xor(a5, 32);
  a6 += __shfl_xor(a6, 8); a6 += __shfl_xor(a6, 16); a6 += __shfl_xor(a6, 32);
  a7 += __shfl_xor(a7, 8); a7 += __shfl_xor(a7, 16); a7 += __shfl_xor(a7, 32);

  dn -= (float)((end - start) - cnt[node]);  // remove pad contributions
  float inv = 1.f / dn;
  if (g == 0 && s >= 4) {  // V lanes of group 0: dims 8(s-4)..8(s-4)+7
    float* op = out + (size_t)node * HD + head * 32 + (s - 4) * 8;
    float4 o0 = make_float4(a0 * inv, a1 * inv, a2 * inv, a3 * inv);
    float4 o1 = make_float4(a4 * inv, a5 * inv, a6 * inv, a7 * inv);
    *(float4*)op = o0;
    *(float4*)(op + 4) = o1;
  }
}

extern "C" void kernel_launch(void* const* d_in, const int* in_sizes, int n_in,
                              void* d_out, int out_size, void* d_ws,
                              size_t ws_size, hipStream_t stream) {
  const float* h = (const float*)d_in[0];
  const int* edge = (const int*)d_in[1];
  const float* WQ = (const float*)d_in[2];
  const float* WK = (const float*)d_in[3];
  const float* WV = (const float*)d_in[4];
  float* out = (float*)d_out;

  int n_node = in_sizes[0] / D_IN;
  int n_edge = in_sizes[1] / 2;
  const int* row = edge;
  const int* col = edge + n_edge;

  char* ws = (char*)d_ws;
  size_t off = 0;
  auto alloc = [&](size_t bytes) {
    void* p = ws + off;
    off += (bytes + 255) & ~(size_t)255;
    return p;
  };
  int nt_total = (n_node + 15) / 16;  // 3125 (50000 = 3125*16 exactly)
  int cap = n_edge + 15 * n_node;     // padded col_sorted capacity
  __hip_bfloat16* Qh = (__hip_bfloat16*)alloc((size_t)NH * n_node * 32 * 2);
  __hip_bfloat16* KVh = (__hip_bfloat16*)alloc((size_t)NH * (n_node + 1) * 64 * 2);
  short8* Bbuf = (short8*)alloc((size_t)48 * 4 * 64 * 16);
  int* col_sorted = (int*)alloc((size_t)cap * 4);
  int* rank = (int*)alloc((size_t)n_edge * 4);
  int* cnt = (int*)alloc((size_t)n_node * 4);
  int* offsets = (int*)alloc((size_t)(n_node + 1) * 4);
  int* bsum = (int*)alloc(256 * 4);

  hipMemsetAsync(cnt, 0, (size_t)n_node * 4, stream);

  prep_w_kernel<<<48, 256, 0, stream>>>(WQ, WK, WV, Bbuf);
  gemm_qkv_kernel<<<nt_total, 256, 0, stream>>>(h, Bbuf, Qh, KVh, nt_total,
                                                n_node);
  fill_kernel<<<(cap + 255) / 256, 256, 0, stream>>>(col_sorted, cap, KVh,
                                                     n_node);

  int nb_e = (n_edge + 255) / 256;
  rank_kernel<<<nb_e, 256, 0, stream>>>(row, n_edge, cnt, rank);

  int nb = (n_node + 255) / 256;
  scan1_kernel<<<nb, 256, 0, stream>>>(cnt, n_node, offsets, bsum);
  scan2_kernel<<<1, 256, 0, stream>>>(bsum, nb);
  scan3_kernel<<<nb, 256, 0, stream>>>(offsets, bsum, cnt, n_node);

  scatter_kernel<<<nb_e, 256, 0, stream>>>(row, col, rank, n_edge, offsets,
                                           col_sorted);

  attn_kernel<<<((n_node + 3) / 4) * 8, 256, 0, stream>>>(
      Qh, KVh, offsets, cnt, col_sorted, out, n_node);
}

// Round 17
// 358.422 us; speedup vs baseline: 1.2670x; 1.0511x over previous
//
#include <hip/hip_runtime.h>
#include <hip/hip_bf16.h>
#include <cstdint>

#define D_IN 128
#define DK 32
#define NH 8
#define HD 256   // NH*DK

typedef __attribute__((ext_vector_type(8))) short short8;
typedef __attribute__((ext_vector_type(4))) float f32x4;

__device__ inline float u2f(unsigned int u) {
  union { unsigned int i; float f; } c; c.i = u; return c.f;
}
__device__ inline short f2bf(float f) {
  union { float f; unsigned int i; } c; c.f = f;
  unsigned int u = c.i;
  u = u + 0x7FFFu + ((u >> 16) & 1u);  // RNE
  return (short)(u >> 16);
}
// DPP quad-perm (explicit lane selects; 0xB1=(1,0,3,2)=xor1, 0x4E=(2,3,0,1)=xor2)
#define DPPF(x, ctrl)                                                         \
  ({                                                                          \
    union { float f; int i; } _a, _r;                                         \
    _a.f = (x);                                                               \
    _r.i = __builtin_amdgcn_update_dpp(0, _a.i, (ctrl), 0xF, 0xF, true);      \
    _r.f;                                                                     \
  })

// ---------- prep B: Wcat[128][768] -> bf16 MFMA B-fragments ----------
__global__ __launch_bounds__(256) void prep_w_kernel(
    const float* __restrict__ WQ, const float* __restrict__ WK,
    const float* __restrict__ WV, short8* __restrict__ Bbuf) {
  int ct = blockIdx.x;  // 0..47
  int t = threadIdx.x;
  int kt = t >> 6, L = t & 63;
  int col = ct * 16 + (L & 15);
  int type = col >> 8;
  const float* W = (type == 0) ? WQ : (type == 1) ? WK : WV;
  int head = (col & 255) >> 5;
  int kk = col & 31;
  int k0 = kt * 32 + ((L >> 4) << 3);
  short8 o;
  #pragma unroll
  for (int r = 0; r < 8; r++)
    o[r] = f2bf(W[head * (D_IN * DK) + (k0 + r) * DK + kk]);
  Bbuf[(size_t)(ct * 4 + kt) * 64 + L] = o;
}

// ---------- MFMA GEMM: head-major Qh (PRE-SCALED by 1/sqrt(32)*log2e) + KVh ----------
// Qh[head][node][32]; KVh[head][node][64] (128B rows: K32|V32).
__global__ __launch_bounds__(256) void gemm_qkv_kernel(
    const float* __restrict__ h, const short8* __restrict__ Bbuf,
    __hip_bfloat16* __restrict__ Qh, __hip_bfloat16* __restrict__ KVh,
    int nt_total, int n_node) {
  __shared__ float hs[16][132];
  __shared__ short lds[16][768];  // Q 0-255 | K 256-511 | V 512-767 (head-major)
  int nt = blockIdx.x;
  int t = threadIdx.x;
  {
    const float4* h4 = (const float4*)(h + (size_t)nt * 16 * 128);
    float4 v0 = h4[t * 2], v1 = h4[t * 2 + 1];
    int node = t >> 4, dim = (t & 15) * 8;
    hs[node][dim + 0] = v0.x; hs[node][dim + 1] = v0.y;
    hs[node][dim + 2] = v0.z; hs[node][dim + 3] = v0.w;
    hs[node][dim + 4] = v1.x; hs[node][dim + 5] = v1.y;
    hs[node][dim + 6] = v1.z; hs[node][dim + 7] = v1.w;
  }
  __syncthreads();
  int w = t >> 6;
  int L = t & 63;
  int arow = L & 15, k0base = ((L >> 4) << 3);
  short8 afrag[4];
  #pragma unroll
  for (int kt = 0; kt < 4; kt++) {
    #pragma unroll
    for (int r = 0; r < 8; r++)
      afrag[kt][r] = f2bf(hs[arow][kt * 32 + k0base + r]);
  }
  f32x4 acc[12];
  #pragma unroll
  for (int c = 0; c < 12; c++) acc[c] = (f32x4){0.f, 0.f, 0.f, 0.f};
  #pragma unroll
  for (int kt = 0; kt < 4; kt++) {
    #pragma unroll
    for (int c = 0; c < 12; c++) {
      short8 b = Bbuf[(size_t)((w * 12 + c) * 4 + kt) * 64 + L];
      acc[c] = __builtin_amdgcn_mfma_f32_16x16x32_bf16(afrag[kt], b, acc[c], 0, 0, 0);
    }
  }
  int row0 = (L >> 4) << 2;
  int col0 = w * 192 + (L & 15);
  const float QSL = 0.25506966f;  // (1/sqrt(32)) * log2(e)
  #pragma unroll
  for (int c = 0; c < 12; c++) {
    float sc = ((w * 192 + c * 16) < 256) ? QSL : 1.f;  // Q cols pre-scaled
    #pragma unroll
    for (int r = 0; r < 4; r++)
      lds[row0 + r][col0 + c * 16] = f2bf(acc[c][r] * sc);
  }
  __syncthreads();
  // Qh out
  #pragma unroll
  for (int j = 0; j < 2; j++) {
    int u = t + j * 256;
    int hh = u >> 6, r2 = (u >> 2) & 15, part = u & 3;
    float4 vdat = *(const float4*)&lds[r2][hh * 32 + part * 8];
    *(float4*)(Qh + ((size_t)hh * n_node + nt * 16 + r2) * 32 + part * 8) = vdat;
  }
  // KVh out
  #pragma unroll
  for (int j = 0; j < 4; j++) {
    int u = t + j * 256;
    int hh = u >> 7, r2 = (u >> 3) & 15, part = u & 7;
    int srccol = (part < 4) ? (256 + hh * 32 + part * 8)
                            : (512 + hh * 32 + (part - 4) * 8);
    float4 vdat = *(const float4*)&lds[r2][srccol];
    *(float4*)(KVh + ((size_t)hh * n_node + nt * 16 + r2) * 64 +
               ((part < 4) ? part * 8 : 32 + (part - 4) * 8)) = vdat;
  }
}

// ---------------- CSR build ----------------
__global__ void rank_kernel(const int* __restrict__ row, int n_edge,
                            int* __restrict__ cnt, int* __restrict__ rank) {
  int i = blockIdx.x * blockDim.x + threadIdx.x;
  if (i < n_edge) rank[i] = atomicAdd(&cnt[row[i]], 1);
}

__global__ __launch_bounds__(256) void scan1_kernel(
    const int* __restrict__ cnt, int n, int* __restrict__ exc,
    int* __restrict__ bsum) {
  __shared__ int s[256];
  int gid = blockIdx.x * 256 + threadIdx.x;
  int v = (gid < n) ? cnt[gid] : 0;
  s[threadIdx.x] = v;
  __syncthreads();
  #pragma unroll
  for (int off = 1; off < 256; off <<= 1) {
    int t = (threadIdx.x >= off) ? s[threadIdx.x - off] : 0;
    __syncthreads();
    s[threadIdx.x] += t;
    __syncthreads();
  }
  if (gid < n) exc[gid] = s[threadIdx.x] - v;
  if (threadIdx.x == 255) bsum[blockIdx.x] = s[255];
}

__global__ __launch_bounds__(256) void scan2_kernel(int* __restrict__ bsum,
                                                    int nb) {
  __shared__ int s[256];
  int v = (threadIdx.x < nb) ? bsum[threadIdx.x] : 0;
  s[threadIdx.x] = v;
  __syncthreads();
  #pragma unroll
  for (int off = 1; off < 256; off <<= 1) {
    int t = (threadIdx.x >= off) ? s[threadIdx.x - off] : 0;
    __syncthreads();
    s[threadIdx.x] += t;
    __syncthreads();
  }
  if (threadIdx.x < nb) bsum[threadIdx.x] = s[threadIdx.x] - v;
}

__global__ __launch_bounds__(256) void scan3_kernel(
    int* __restrict__ exc, const int* __restrict__ bsum, int n, int n_edge) {
  int gid = blockIdx.x * 256 + threadIdx.x;
  if (gid < n) exc[gid] = exc[gid] + bsum[blockIdx.x];
  if (gid == 0) exc[n] = n_edge;
}

__global__ void scatter_kernel(const int* __restrict__ row,
                               const int* __restrict__ col,
                               const int* __restrict__ rank, int n_edge,
                               const int* __restrict__ offsets,
                               int* __restrict__ col_sorted) {
  int i = blockIdx.x * blockDim.x + threadIdx.x;
  if (i < n_edge) col_sorted[offsets[row[i]] + rank[i]] = col[i];
}

// ---------------- Attention: head-partitioned, masked loop (r12 base + safe trims) ----------------
// head = blockIdx%8 (XCD-pinned 6.4MB KVh slice; FETCH-halving proven r11/r12).
// Lane l: g=l>>3 edge slot, s=l&7 (0-3: K dims 8s.., 4-7: V dims 8(s-4)..).
// Col loads: r12-proven select form (two scalar loads). xor1/xor2 via DPP
// quad_perm; K->V transfer via __shfl_xor(d,4) (r12-proven). Qh pre-scaled by
// 1/sqrt(32)*log2e -> p = exp2f(lg) (r14-proven). Masked p keeps dn exact.
#define PROC(r, vld)                                                         \
  {                                                                          \
    float x0 = u2f(r.x << 16), x1 = u2f(r.x & 0xFFFF0000u);                  \
    float x2 = u2f(r.y << 16), x3 = u2f(r.y & 0xFFFF0000u);                  \
    float x4 = u2f(r.z << 16), x5 = u2f(r.z & 0xFFFF0000u);                  \
    float x6 = u2f(r.w << 16), x7 = u2f(r.w & 0xFFFF0000u);                  \
    float d = x0 * qf0;                                                      \
    d = fmaf(x1, qf1, d); d = fmaf(x2, qf2, d); d = fmaf(x3, qf3, d);        \
    d = fmaf(x4, qf4, d); d = fmaf(x5, qf5, d); d = fmaf(x6, qf6, d);        \
    d = fmaf(x7, qf7, d);                                                    \
    d += DPPF(d, 0xB1);              /* xor1: quad_perm(1,0,3,2) */          \
    d += DPPF(d, 0x4E);              /* xor2: quad_perm(2,3,0,1) */          \
    float tt = __shfl_xor(d, 4);     /* K->V transfer, proven r12 */         \
    float lg = (s < 4) ? d : tt;                                             \
    float p = (vld) ? exp2f(lg) : 0.f;                                       \
    dn += p;                                                                 \
    a0 = fmaf(p, x0, a0); a1 = fmaf(p, x1, a1);                              \
    a2 = fmaf(p, x2, a2); a3 = fmaf(p, x3, a3);                              \
    a4 = fmaf(p, x4, a4); a5 = fmaf(p, x5, a5);                              \
    a6 = fmaf(p, x6, a6); a7 = fmaf(p, x7, a7);                              \
  }

__global__ __launch_bounds__(256) void attn_kernel(
    const __hip_bfloat16* __restrict__ Qh, const __hip_bfloat16* __restrict__ KVh,
    const int* __restrict__ offsets, const int* __restrict__ col_sorted,
    float* __restrict__ out, int n_node) {
  int head = blockIdx.x & 7;   // XCD-pinned
  int grp = blockIdx.x >> 3;
  int wv = threadIdx.x >> 6;
  int lane = threadIdx.x & 63;
  int g = lane >> 3;  // edge slot 0..7
  int s = lane & 7;   // 0-3: K dims 8s..; 4-7: V dims 8(s-4)..
  int node = grp * 4 + wv;
  if (node >= n_node) return;
  int start = offsets[node], end = offsets[node + 1];

  if (end <= start) {
    if (g == 0 && s >= 4) {
      float* op = out + (size_t)node * HD + head * 32 + (s - 4) * 8;
      float4 z = make_float4(0.f, 0.f, 0.f, 0.f);
      *(float4*)op = z;
      *(float4*)(op + 4) = z;
    }
    return;
  }

  float qf0, qf1, qf2, qf3, qf4, qf5, qf6, qf7;
  {
    uint4 qr = *(const uint4*)((const char*)(Qh +
                ((size_t)head * n_node + node) * 32) + (s & 3) * 16);
    qf0 = u2f(qr.x << 16); qf1 = u2f(qr.x & 0xFFFF0000u);
    qf2 = u2f(qr.y << 16); qf3 = u2f(qr.y & 0xFFFF0000u);
    qf4 = u2f(qr.z << 16); qf5 = u2f(qr.z & 0xFFFF0000u);
    qf6 = u2f(qr.w << 16); qf7 = u2f(qr.w & 0xFFFF0000u);
  }
  float dn = 0.f;
  float a0 = 0.f, a1 = 0.f, a2 = 0.f, a3 = 0.f;
  float a4 = 0.f, a5 = 0.f, a6 = 0.f, a7 = 0.f;

  // wave-uniform base + 32-bit lane offsets
  const char* kvb = (const char*)KVh + (size_t)head * n_node * 128;
  unsigned int soff = (unsigned int)s << 4;

  for (int base = start; base < end; base += 16) {
    int i0 = base + g, i1 = base + 8 + g;
    bool v0 = i0 < end, v1 = i1 < end;
    int c0 = col_sorted[v0 ? i0 : start];
    int c1 = col_sorted[v1 ? i1 : start];
    unsigned int b0 = ((unsigned int)c0 << 7) + soff;
    unsigned int b1 = ((unsigned int)c1 << 7) + soff;
    uint4 r0 = *(const uint4*)(kvb + b0);
    uint4 r1 = *(const uint4*)(kvb + b1);
    PROC(r0, v0);
    PROC(r1, v1);
  }

  // merge the 8 edge slots: proven shfl_xor ladder (once per node)
  dn += __shfl_xor(dn, 8); dn += __shfl_xor(dn, 16); dn += __shfl_xor(dn, 32);
  a0 += __shfl_xor(a0, 8); a0 += __shfl_xor(a0, 16); a0 += __shfl_xor(a0, 32);
  a1 += __shfl_xor(a1, 8); a1 += __shfl_xor(a1, 16); a1 += __shfl_xor(a1, 32);
  a2 += __shfl_xor(a2, 8); a2 += __shfl_xor(a2, 16); a2 += __shfl_xor(a2, 32);
  a3 += __shfl_xor(a3, 8); a3 += __shfl_xor(a3, 16); a3 += __shfl_xor(a3, 32);
  a4 += __shfl_xor(a4, 8); a4 += __shfl_xor(a4, 16); a4 += __shfl_xor(a4, 32);
  a5 += __shfl_xor(a5, 8); a5 += __shfl_xor(a5, 16); a5 += __shfl_xor(a5, 32);
  a6 += __shfl_xor(a6, 8); a6 += __shfl_xor(a6, 16); a6 += __shfl_xor(a6, 32);
  a7 += __shfl_xor(a7, 8); a7 += __shfl_xor(a7, 16); a7 += __shfl_xor(a7, 32);

  float inv = 1.f / dn;
  if (g == 0 && s >= 4) {  // V lanes of slot 0: dims 8(s-4)..8(s-4)+7
    float* op = out + (size_t)node * HD + head * 32 + (s - 4) * 8;
    float4 o0 = make_float4(a0 * inv, a1 * inv, a2 * inv, a3 * inv);
    float4 o1 = make_float4(a4 * inv, a5 * inv, a6 * inv, a7 * inv);
    *(float4*)op = o0;
    *(float4*)(op + 4) = o1;
  }
}

extern "C" void kernel_launch(void* const* d_in, const int* in_sizes, int n_in,
                              void* d_out, int out_size, void* d_ws,
                              size_t ws_size, hipStream_t stream) {
  const float* h = (const float*)d_in[0];
  const int* edge = (const int*)d_in[1];
  const float* WQ = (const float*)d_in[2];
  const float* WK = (const float*)d_in[3];
  const float* WV = (const float*)d_in[4];
  float* out = (float*)d_out;

  int n_node = in_sizes[0] / D_IN;
  int n_edge = in_sizes[1] / 2;
  const int* row = edge;
  const int* col = edge + n_edge;

  char* ws = (char*)d_ws;
  size_t off = 0;
  auto alloc = [&](size_t bytes) {
    void* p = ws + off;
    off += (bytes + 255) & ~(size_t)255;
    return p;
  };
  int nt_total = (n_node + 15) / 16;  // 3125 (50000 = 3125*16 exactly)
  __hip_bfloat16* Qh = (__hip_bfloat16*)alloc((size_t)NH * n_node * 32 * 2);
  __hip_bfloat16* KVh = (__hip_bfloat16*)alloc((size_t)NH * n_node * 64 * 2);
  short8* Bbuf = (short8*)alloc((size_t)48 * 4 * 64 * 16);
  int* col_sorted = (int*)alloc((size_t)n_edge * 4);
  int* rank = (int*)alloc((size_t)n_edge * 4);
  int* cnt = (int*)alloc((size_t)n_node * 4);
  int* offsets = (int*)alloc((size_t)(n_node + 1) * 4);
  int* bsum = (int*)alloc(256 * 4);

  hipMemsetAsync(cnt, 0, (size_t)n_node * 4, stream);

  prep_w_kernel<<<48, 256, 0, stream>>>(WQ, WK, WV, Bbuf);
  gemm_qkv_kernel<<<nt_total, 256, 0, stream>>>(h, Bbuf, Qh, KVh, nt_total,
                                                n_node);

  int nb_e = (n_edge + 255) / 256;
  rank_kernel<<<nb_e, 256, 0, stream>>>(row, n_edge, cnt, rank);

  int nb = (n_node + 255) / 256;
  scan1_kernel<<<nb, 256, 0, stream>>>(cnt, n_node, offsets, bsum);
  scan2_kernel<<<1, 256, 0, stream>>>(bsum, nb);
  scan3_kernel<<<nb, 256, 0, stream>>>(offsets, bsum, n_node, n_edge);

  scatter_kernel<<<nb_e, 256, 0, stream>>>(row, col, rank, n_edge, offsets,
                                           col_sorted);

  attn_kernel<<<((n_node + 3) / 4) * 8, 256, 0, stream>>>(
      Qh, KVh, offsets, col_sorted, out, n_node);
}

// Round 18
// 345.771 us; speedup vs baseline: 1.3134x; 1.0366x over previous
//
#include <hip/hip_runtime.h>
#include <hip/hip_bf16.h>
#include <cstdint>

#define D_IN 128
#define DK 32
#define NH 8
#define HD 256   // NH*DK

typedef __attribute__((ext_vector_type(8))) short short8;
typedef __attribute__((ext_vector_type(4))) float f32x4;
typedef _Float16 h2v __attribute__((ext_vector_type(2)));

__device__ inline float u2f(unsigned int u) {
  union { unsigned int i; float f; } c; c.i = u; return c.f;
}
__device__ inline short f2bf(float f) {
  union { float f; unsigned int i; } c; c.f = f;
  unsigned int u = c.i;
  u = u + 0x7FFFu + ((u >> 16) & 1u);  // RNE
  return (short)(u >> 16);
}
__device__ inline short f2h(float f) {
  union { _Float16 h; short s; } c; c.h = (_Float16)f; return c.s;
}
__device__ inline h2v u2h2(unsigned int u) {
  union { unsigned int u; h2v h; } c; c.u = u; return c.h;
}

// ---------- prep B: Wcat[128][768] -> bf16 MFMA B-fragments (MFMA stays bf16) ----------
__global__ __launch_bounds__(256) void prep_w_kernel(
    const float* __restrict__ WQ, const float* __restrict__ WK,
    const float* __restrict__ WV, short8* __restrict__ Bbuf) {
  int ct = blockIdx.x;  // 0..47
  int t = threadIdx.x;
  int kt = t >> 6, L = t & 63;
  int col = ct * 16 + (L & 15);
  int type = col >> 8;
  const float* W = (type == 0) ? WQ : (type == 1) ? WK : WV;
  int head = (col & 255) >> 5;
  int kk = col & 31;
  int k0 = kt * 32 + ((L >> 4) << 3);
  short8 o;
  #pragma unroll
  for (int r = 0; r < 8; r++)
    o[r] = f2bf(W[head * (D_IN * DK) + (k0 + r) * DK + kk]);
  Bbuf[(size_t)(ct * 4 + kt) * 64 + L] = o;
}

// ---------- MFMA GEMM: head-major Qh/KVh in F16 (Qh PRE-SCALED by 1/sqrt(32)*log2e) ----------
// Qh[head][node][32] f16; KVh[head][node][64] f16 (128B rows: K32|V32).
__global__ __launch_bounds__(256) void gemm_qkv_kernel(
    const float* __restrict__ h, const short8* __restrict__ Bbuf,
    short* __restrict__ Qh, short* __restrict__ KVh,
    int nt_total, int n_node) {
  __shared__ float hs[16][132];
  __shared__ short lds[16][768];  // Q 0-255 | K 256-511 | V 512-767 (head-major), f16 bits
  int nt = blockIdx.x;
  int t = threadIdx.x;
  {
    const float4* h4 = (const float4*)(h + (size_t)nt * 16 * 128);
    float4 v0 = h4[t * 2], v1 = h4[t * 2 + 1];
    int node = t >> 4, dim = (t & 15) * 8;
    hs[node][dim + 0] = v0.x; hs[node][dim + 1] = v0.y;
    hs[node][dim + 2] = v0.z; hs[node][dim + 3] = v0.w;
    hs[node][dim + 4] = v1.x; hs[node][dim + 5] = v1.y;
    hs[node][dim + 6] = v1.z; hs[node][dim + 7] = v1.w;
  }
  __syncthreads();
  int w = t >> 6;
  int L = t & 63;
  int arow = L & 15, k0base = ((L >> 4) << 3);
  short8 afrag[4];
  #pragma unroll
  for (int kt = 0; kt < 4; kt++) {
    #pragma unroll
    for (int r = 0; r < 8; r++)
      afrag[kt][r] = f2bf(hs[arow][kt * 32 + k0base + r]);
  }
  f32x4 acc[12];
  #pragma unroll
  for (int c = 0; c < 12; c++) acc[c] = (f32x4){0.f, 0.f, 0.f, 0.f};
  #pragma unroll
  for (int kt = 0; kt < 4; kt++) {
    #pragma unroll
    for (int c = 0; c < 12; c++) {
      short8 b = Bbuf[(size_t)((w * 12 + c) * 4 + kt) * 64 + L];
      acc[c] = __builtin_amdgcn_mfma_f32_16x16x32_bf16(afrag[kt], b, acc[c], 0, 0, 0);
    }
  }
  int row0 = (L >> 4) << 2;
  int col0 = w * 192 + (L & 15);
  const float QSL = 0.25506966f;  // (1/sqrt(32)) * log2(e)
  #pragma unroll
  for (int c = 0; c < 12; c++) {
    float sc = ((w * 192 + c * 16) < 256) ? QSL : 1.f;  // Q cols pre-scaled
    #pragma unroll
    for (int r = 0; r < 4; r++)
      lds[row0 + r][col0 + c * 16] = f2h(acc[c][r] * sc);  // store f16 bits
  }
  __syncthreads();
  // Qh out
  #pragma unroll
  for (int j = 0; j < 2; j++) {
    int u = t + j * 256;
    int hh = u >> 6, r2 = (u >> 2) & 15, part = u & 3;
    float4 vdat = *(const float4*)&lds[r2][hh * 32 + part * 8];
    *(float4*)(Qh + ((size_t)hh * n_node + nt * 16 + r2) * 32 + part * 8) = vdat;
  }
  // KVh out
  #pragma unroll
  for (int j = 0; j < 4; j++) {
    int u = t + j * 256;
    int hh = u >> 7, r2 = (u >> 3) & 15, part = u & 7;
    int srccol = (part < 4) ? (256 + hh * 32 + part * 8)
                            : (512 + hh * 32 + (part - 4) * 8);
    float4 vdat = *(const float4*)&lds[r2][srccol];
    *(float4*)(KVh + ((size_t)hh * n_node + nt * 16 + r2) * 64 +
               ((part < 4) ? part * 8 : 32 + (part - 4) * 8)) = vdat;
  }
}

// ---------------- CSR build ----------------
__global__ void rank_kernel(const int* __restrict__ row, int n_edge,
                            int* __restrict__ cnt, int* __restrict__ rank) {
  int i = blockIdx.x * blockDim.x + threadIdx.x;
  if (i < n_edge) rank[i] = atomicAdd(&cnt[row[i]], 1);
}

__global__ __launch_bounds__(256) void scan1_kernel(
    const int* __restrict__ cnt, int n, int* __restrict__ exc,
    int* __restrict__ bsum) {
  __shared__ int s[256];
  int gid = blockIdx.x * 256 + threadIdx.x;
  int v = (gid < n) ? cnt[gid] : 0;
  s[threadIdx.x] = v;
  __syncthreads();
  #pragma unroll
  for (int off = 1; off < 256; off <<= 1) {
    int t = (threadIdx.x >= off) ? s[threadIdx.x - off] : 0;
    __syncthreads();
    s[threadIdx.x] += t;
    __syncthreads();
  }
  if (gid < n) exc[gid] = s[threadIdx.x] - v;
  if (threadIdx.x == 255) bsum[blockIdx.x] = s[255];
}

__global__ __launch_bounds__(256) void scan2_kernel(int* __restrict__ bsum,
                                                    int nb) {
  __shared__ int s[256];
  int v = (threadIdx.x < nb) ? bsum[threadIdx.x] : 0;
  s[threadIdx.x] = v;
  __syncthreads();
  #pragma unroll
  for (int off = 1; off < 256; off <<= 1) {
    int t = (threadIdx.x >= off) ? s[threadIdx.x - off] : 0;
    __syncthreads();
    s[threadIdx.x] += t;
    __syncthreads();
  }
  if (threadIdx.x < nb) bsum[threadIdx.x] = s[threadIdx.x] - v;
}

__global__ __launch_bounds__(256) void scan3_kernel(
    int* __restrict__ exc, const int* __restrict__ bsum, int n, int n_edge) {
  int gid = blockIdx.x * 256 + threadIdx.x;
  if (gid < n) exc[gid] = exc[gid] + bsum[blockIdx.x];
  if (gid == 0) exc[n] = n_edge;
}

__global__ void scatter_kernel(const int* __restrict__ row,
                               const int* __restrict__ col,
                               const int* __restrict__ rank, int n_edge,
                               const int* __restrict__ offsets,
                               int* __restrict__ col_sorted) {
  int i = blockIdx.x * blockDim.x + threadIdx.x;
  if (i < n_edge) col_sorted[offsets[row[i]] + rank[i]] = col[i];
}

// ---------------- Attention: r17 structure + f16 packed-dot (v_dot2_f32_f16) ----------------
// head = blockIdx%8 (XCD-pinned 6.4MB KVh slice; FETCH-halving proven r11/r12).
// Lane l: g=l>>3 edge slot, s=l&7 (0-3: K dims 8s.., 4-7: V dims 8(s-4)..).
// Dot: 4x __builtin_amdgcn_fdot2 on packed f16 (no unpack, half the FMAs).
// xor1/xor2 via DPP quad_perm; K->V transfer via __shfl_xor(d,4) (r12-proven).
// Qh pre-scaled by 1/sqrt(32)*log2e -> p = exp2f(lg). Masked p keeps dn exact.
#define PROC(r, vld)                                                         \
  {                                                                          \
    h2v k0 = u2h2(r.x), k1 = u2h2(r.y), k2 = u2h2(r.z), k3 = u2h2(r.w);      \
    float d = __builtin_amdgcn_fdot2(k3, q3, 0.f, false);                    \
    d = __builtin_amdgcn_fdot2(k2, q2, d, false);                            \
    d = __builtin_amdgcn_fdot2(k1, q1, d, false);                            \
    d = __builtin_amdgcn_fdot2(k0, q0, d, false);                            \
    d += DPPF(d, 0xB1);              /* xor1: quad_perm(1,0,3,2) */          \
    d += DPPF(d, 0x4E);              /* xor2: quad_perm(2,3,0,1) */          \
    float tt = __shfl_xor(d, 4);     /* K->V transfer, proven r12 */         \
    float lg = (s < 4) ? d : tt;                                             \
    float p = (vld) ? exp2f(lg) : 0.f;                                       \
    float x0 = (float)k0[0], x1 = (float)k0[1];                              \
    float x2 = (float)k1[0], x3 = (float)k1[1];                              \
    float x4 = (float)k2[0], x5 = (float)k2[1];                              \
    float x6 = (float)k3[0], x7 = (float)k3[1];                              \
    dn += p;                                                                 \
    a0 = fmaf(p, x0, a0); a1 = fmaf(p, x1, a1);                              \
    a2 = fmaf(p, x2, a2); a3 = fmaf(p, x3, a3);                              \
    a4 = fmaf(p, x4, a4); a5 = fmaf(p, x5, a5);                              \
    a6 = fmaf(p, x6, a6); a7 = fmaf(p, x7, a7);                              \
  }

// DPP quad-perm (explicit lane selects; 0xB1=(1,0,3,2)=xor1, 0x4E=(2,3,0,1)=xor2)
#define DPPF(x, ctrl)                                                         \
  ({                                                                          \
    union { float f; int i; } _a, _r;                                         \
    _a.f = (x);                                                               \
    _r.i = __builtin_amdgcn_update_dpp(0, _a.i, (ctrl), 0xF, 0xF, true);      \
    _r.f;                                                                     \
  })

__global__ __launch_bounds__(256) void attn_kernel(
    const short* __restrict__ Qh, const short* __restrict__ KVh,
    const int* __restrict__ offsets, const int* __restrict__ col_sorted,
    float* __restrict__ out, int n_node) {
  int head = blockIdx.x & 7;   // XCD-pinned
  int grp = blockIdx.x >> 3;
  int wv = threadIdx.x >> 6;
  int lane = threadIdx.x & 63;
  int g = lane >> 3;  // edge slot 0..7
  int s = lane & 7;   // 0-3: K dims 8s..; 4-7: V dims 8(s-4)..
  int node = grp * 4 + wv;
  if (node >= n_node) return;
  int start = offsets[node], end = offsets[node + 1];

  if (end <= start) {
    if (g == 0 && s >= 4) {
      float* op = out + (size_t)node * HD + head * 32 + (s - 4) * 8;
      float4 z = make_float4(0.f, 0.f, 0.f, 0.f);
      *(float4*)op = z;
      *(float4*)(op + 4) = z;
    }
    return;
  }

  // q chunk (s&3): 8 f16 kept PACKED (pre-scaled at GEMM)
  h2v q0, q1, q2, q3;
  {
    uint4 qr = *(const uint4*)((const char*)(Qh +
                ((size_t)head * n_node + node) * 32) + (s & 3) * 16);
    q0 = u2h2(qr.x); q1 = u2h2(qr.y); q2 = u2h2(qr.z); q3 = u2h2(qr.w);
  }
  float dn = 0.f;
  float a0 = 0.f, a1 = 0.f, a2 = 0.f, a3 = 0.f;
  float a4 = 0.f, a5 = 0.f, a6 = 0.f, a7 = 0.f;

  // wave-uniform base + 32-bit lane offsets
  const char* kvb = (const char*)KVh + (size_t)head * n_node * 128;
  unsigned int soff = (unsigned int)s << 4;

  for (int base = start; base < end; base += 16) {
    int i0 = base + g, i1 = base + 8 + g;
    bool v0 = i0 < end, v1 = i1 < end;
    int c0 = col_sorted[v0 ? i0 : start];
    int c1 = col_sorted[v1 ? i1 : start];
    unsigned int b0 = ((unsigned int)c0 << 7) + soff;
    unsigned int b1 = ((unsigned int)c1 << 7) + soff;
    uint4 r0 = *(const uint4*)(kvb + b0);
    uint4 r1 = *(const uint4*)(kvb + b1);
    PROC(r0, v0);
    PROC(r1, v1);
  }

  // merge the 8 edge slots: proven shfl_xor ladder (once per node)
  dn += __shfl_xor(dn, 8); dn += __shfl_xor(dn, 16); dn += __shfl_xor(dn, 32);
  a0 += __shfl_xor(a0, 8); a0 += __shfl_xor(a0, 16); a0 += __shfl_xor(a0, 32);
  a1 += __shfl_xor(a1, 8); a1 += __shfl_xor(a1, 16); a1 += __shfl_xor(a1, 32);
  a2 += __shfl_xor(a2, 8); a2 += __shfl_xor(a2, 16); a2 += __shfl_xor(a2, 32);
  a3 += __shfl_xor(a3, 8); a3 += __shfl_xor(a3, 16); a3 += __shfl_xor(a3, 32);
  a4 += __shfl_xor(a4, 8); a4 += __shfl_xor(a4, 16); a4 += __shfl_xor(a4, 32);
  a5 += __shfl_xor(a5, 8); a5 += __shfl_xor(a5, 16); a5 += __shfl_xor(a5, 32);
  a6 += __shfl_xor(a6, 8); a6 += __shfl_xor(a6, 16); a6 += __shfl_xor(a6, 32);
  a7 += __shfl_xor(a7, 8); a7 += __shfl_xor(a7, 16); a7 += __shfl_xor(a7, 32);

  float inv = 1.f / dn;
  if (g == 0 && s >= 4) {  // V lanes of slot 0: dims 8(s-4)..8(s-4)+7
    float* op = out + (size_t)node * HD + head * 32 + (s - 4) * 8;
    float4 o0 = make_float4(a0 * inv, a1 * inv, a2 * inv, a3 * inv);
    float4 o1 = make_float4(a4 * inv, a5 * inv, a6 * inv, a7 * inv);
    *(float4*)op = o0;
    *(float4*)(op + 4) = o1;
  }
}

extern "C" void kernel_launch(void* const* d_in, const int* in_sizes, int n_in,
                              void* d_out, int out_size, void* d_ws,
                              size_t ws_size, hipStream_t stream) {
  const float* h = (const float*)d_in[0];
  const int* edge = (const int*)d_in[1];
  const float* WQ = (const float*)d_in[2];
  const float* WK = (const float*)d_in[3];
  const float* WV = (const float*)d_in[4];
  float* out = (float*)d_out;

  int n_node = in_sizes[0] / D_IN;
  int n_edge = in_sizes[1] / 2;
  const int* row = edge;
  const int* col = edge + n_edge;

  char* ws = (char*)d_ws;
  size_t off = 0;
  auto alloc = [&](size_t bytes) {
    void* p = ws + off;
    off += (bytes + 255) & ~(size_t)255;
    return p;
  };
  int nt_total = (n_node + 15) / 16;  // 3125 (50000 = 3125*16 exactly)
  short* Qh = (short*)alloc((size_t)NH * n_node * 32 * 2);
  short* KVh = (short*)alloc((size_t)NH * n_node * 64 * 2);
  short8* Bbuf = (short8*)alloc((size_t)48 * 4 * 64 * 16);
  int* col_sorted = (int*)alloc((size_t)n_edge * 4);
  int* rank = (int*)alloc((size_t)n_edge * 4);
  int* cnt = (int*)alloc((size_t)n_node * 4);
  int* offsets = (int*)alloc((size_t)(n_node + 1) * 4);
  int* bsum = (int*)alloc(256 * 4);

  hipMemsetAsync(cnt, 0, (size_t)n_node * 4, stream);

  prep_w_kernel<<<48, 256, 0, stream>>>(WQ, WK, WV, Bbuf);
  gemm_qkv_kernel<<<nt_total, 256, 0, stream>>>(h, Bbuf, Qh, KVh, nt_total,
                                                n_node);

  int nb_e = (n_edge + 255) / 256;
  rank_kernel<<<nb_e, 256, 0, stream>>>(row, n_edge, cnt, rank);

  int nb = (n_node + 255) / 256;
  scan1_kernel<<<nb, 256, 0, stream>>>(cnt, n_node, offsets, bsum);
  scan2_kernel<<<1, 256, 0, stream>>>(bsum, nb);
  scan3_kernel<<<nb, 256, 0, stream>>>(offsets, bsum, n_node, n_edge);

  scatter_kernel<<<nb_e, 256, 0, stream>>>(row, col, rank, n_edge, offsets,
                                           col_sorted);

  attn_kernel<<<((n_node + 3) / 4) * 8, 256, 0, stream>>>(
      Qh, KVh, offsets, col_sorted, out, n_node);
}

// Round 19
// 316.210 us; speedup vs baseline: 1.4362x; 1.0935x over previous
//
#include <hip/hip_runtime.h>
#include <hip/hip_bf16.h>
#include <cstdint>

#define D_IN 128
#define DK 32
#define NH 8
#define HD 256   // NH*DK

typedef __attribute__((ext_vector_type(8))) short short8;
typedef __attribute__((ext_vector_type(4))) float f32x4;
typedef _Float16 h2v __attribute__((ext_vector_type(2)));

__device__ inline float u2f(unsigned int u) {
  union { unsigned int i; float f; } c; c.i = u; return c.f;
}
__device__ inline short f2bf(float f) {
  union { float f; unsigned int i; } c; c.f = f;
  unsigned int u = c.i;
  u = u + 0x7FFFu + ((u >> 16) & 1u);  // RNE
  return (short)(u >> 16);
}
__device__ inline short f2h(float f) {
  union { _Float16 h; short s; } c; c.h = (_Float16)f; return c.s;
}
__device__ inline h2v u2h2(unsigned int u) {
  union { unsigned int u; h2v h; } c; c.u = u; return c.h;
}
// DPP quad-perm (explicit lane selects; 0xB1=(1,0,3,2)=xor1, 0x4E=(2,3,0,1)=xor2)
#define DPPF(x, ctrl)                                                         \
  ({                                                                          \
    union { float f; int i; } _a, _r;                                         \
    _a.f = (x);                                                               \
    _r.i = __builtin_amdgcn_update_dpp(0, _a.i, (ctrl), 0xF, 0xF, true);      \
    _r.f;                                                                     \
  })

// ---------- prep B: Wcat[128][768] -> bf16 MFMA B-fragments (MFMA stays bf16) ----------
__global__ __launch_bounds__(256) void prep_w_kernel(
    const float* __restrict__ WQ, const float* __restrict__ WK,
    const float* __restrict__ WV, short8* __restrict__ Bbuf) {
  int ct = blockIdx.x;  // 0..47
  int t = threadIdx.x;
  int kt = t >> 6, L = t & 63;
  int col = ct * 16 + (L & 15);
  int type = col >> 8;
  const float* W = (type == 0) ? WQ : (type == 1) ? WK : WV;
  int head = (col & 255) >> 5;
  int kk = col & 31;
  int k0 = kt * 32 + ((L >> 4) << 3);
  short8 o;
  #pragma unroll
  for (int r = 0; r < 8; r++)
    o[r] = f2bf(W[head * (D_IN * DK) + (k0 + r) * DK + kk]);
  Bbuf[(size_t)(ct * 4 + kt) * 64 + L] = o;
}

// ---------- MFMA GEMM: head-major Qh/KVh in F16 (Qh PRE-SCALED by 1/sqrt(32)*log2e) ----------
// Qh[head][node][32] f16; KVh[head][node][64] f16 (128B rows: K32|V32).
__global__ __launch_bounds__(256) void gemm_qkv_kernel(
    const float* __restrict__ h, const short8* __restrict__ Bbuf,
    short* __restrict__ Qh, short* __restrict__ KVh,
    int nt_total, int n_node) {
  __shared__ float hs[16][132];
  __shared__ short lds[16][768];  // Q 0-255 | K 256-511 | V 512-767 (head-major), f16 bits
  int nt = blockIdx.x;
  int t = threadIdx.x;
  {
    const float4* h4 = (const float4*)(h + (size_t)nt * 16 * 128);
    float4 v0 = h4[t * 2], v1 = h4[t * 2 + 1];
    int node = t >> 4, dim = (t & 15) * 8;
    hs[node][dim + 0] = v0.x; hs[node][dim + 1] = v0.y;
    hs[node][dim + 2] = v0.z; hs[node][dim + 3] = v0.w;
    hs[node][dim + 4] = v1.x; hs[node][dim + 5] = v1.y;
    hs[node][dim + 6] = v1.z; hs[node][dim + 7] = v1.w;
  }
  __syncthreads();
  int w = t >> 6;
  int L = t & 63;
  int arow = L & 15, k0base = ((L >> 4) << 3);
  short8 afrag[4];
  #pragma unroll
  for (int kt = 0; kt < 4; kt++) {
    #pragma unroll
    for (int r = 0; r < 8; r++)
      afrag[kt][r] = f2bf(hs[arow][kt * 32 + k0base + r]);
  }
  f32x4 acc[12];
  #pragma unroll
  for (int c = 0; c < 12; c++) acc[c] = (f32x4){0.f, 0.f, 0.f, 0.f};
  #pragma unroll
  for (int kt = 0; kt < 4; kt++) {
    #pragma unroll
    for (int c = 0; c < 12; c++) {
      short8 b = Bbuf[(size_t)((w * 12 + c) * 4 + kt) * 64 + L];
      acc[c] = __builtin_amdgcn_mfma_f32_16x16x32_bf16(afrag[kt], b, acc[c], 0, 0, 0);
    }
  }
  int row0 = (L >> 4) << 2;
  int col0 = w * 192 + (L & 15);
  const float QSL = 0.25506966f;  // (1/sqrt(32)) * log2(e)
  #pragma unroll
  for (int c = 0; c < 12; c++) {
    float sc = ((w * 192 + c * 16) < 256) ? QSL : 1.f;  // Q cols pre-scaled
    #pragma unroll
    for (int r = 0; r < 4; r++)
      lds[row0 + r][col0 + c * 16] = f2h(acc[c][r] * sc);  // store f16 bits
  }
  __syncthreads();
  // Qh out
  #pragma unroll
  for (int j = 0; j < 2; j++) {
    int u = t + j * 256;
    int hh = u >> 6, r2 = (u >> 2) & 15, part = u & 3;
    float4 vdat = *(const float4*)&lds[r2][hh * 32 + part * 8];
    *(float4*)(Qh + ((size_t)hh * n_node + nt * 16 + r2) * 32 + part * 8) = vdat;
  }
  // KVh out
  #pragma unroll
  for (int j = 0; j < 4; j++) {
    int u = t + j * 256;
    int hh = u >> 7, r2 = (u >> 3) & 15, part = u & 7;
    int srccol = (part < 4) ? (256 + hh * 32 + part * 8)
                            : (512 + hh * 32 + (part - 4) * 8);
    float4 vdat = *(const float4*)&lds[r2][srccol];
    *(float4*)(KVh + ((size_t)hh * n_node + nt * 16 + r2) * 64 +
               ((part < 4) ? part * 8 : 32 + (part - 4) * 8)) = vdat;
  }
}

// ---------------- CSR build ----------------
__global__ void rank_kernel(const int* __restrict__ row, int n_edge,
                            int* __restrict__ cnt, int* __restrict__ rank) {
  int i = blockIdx.x * blockDim.x + threadIdx.x;
  if (i < n_edge) rank[i] = atomicAdd(&cnt[row[i]], 1);
}

__global__ __launch_bounds__(256) void scan1_kernel(
    const int* __restrict__ cnt, int n, int* __restrict__ exc,
    int* __restrict__ bsum) {
  __shared__ int s[256];
  int gid = blockIdx.x * 256 + threadIdx.x;
  int v = (gid < n) ? cnt[gid] : 0;
  s[threadIdx.x] = v;
  __syncthreads();
  #pragma unroll
  for (int off = 1; off < 256; off <<= 1) {
    int t = (threadIdx.x >= off) ? s[threadIdx.x - off] : 0;
    __syncthreads();
    s[threadIdx.x] += t;
    __syncthreads();
  }
  if (gid < n) exc[gid] = s[threadIdx.x] - v;
  if (threadIdx.x == 255) bsum[blockIdx.x] = s[255];
}

__global__ __launch_bounds__(256) void scan2_kernel(int* __restrict__ bsum,
                                                    int nb) {
  __shared__ int s[256];
  int v = (threadIdx.x < nb) ? bsum[threadIdx.x] : 0;
  s[threadIdx.x] = v;
  __syncthreads();
  #pragma unroll
  for (int off = 1; off < 256; off <<= 1) {
    int t = (threadIdx.x >= off) ? s[threadIdx.x - off] : 0;
    __syncthreads();
    s[threadIdx.x] += t;
    __syncthreads();
  }
  if (threadIdx.x < nb) bsum[threadIdx.x] = s[threadIdx.x] - v;
}

__global__ __launch_bounds__(256) void scan3_kernel(
    int* __restrict__ exc, const int* __restrict__ bsum, int n, int n_edge) {
  int gid = blockIdx.x * 256 + threadIdx.x;
  if (gid < n) exc[gid] = exc[gid] + bsum[blockIdx.x];
  if (gid == 0) exc[n] = n_edge;
}

__global__ void scatter_kernel(const int* __restrict__ row,
                               const int* __restrict__ col,
                               const int* __restrict__ rank, int n_edge,
                               const int* __restrict__ offsets,
                               int* __restrict__ col_sorted) {
  int i = blockIdx.x * blockDim.x + threadIdx.x;
  if (i < n_edge) col_sorted[offsets[row[i]] + rank[i]] = col[i];
}

// ---------------- Attention: QUAD-per-edge, zero wasted lane-work ----------------
// head = blockIdx%8 (XCD-pinned 6.4MB KVh slice; FETCH-halving proven r11/r12).
// Lane l serves edge base+(l>>2), dim-slice (l&3)*8..+7. Per iter (16 edges):
// load K-half + V-half of OWN edge's 128B row (same line), 4 fdot2, quad
// xor1/xor2 (DPP) -> full 32-dim logit in ALL 4 lanes (no transfer shfl),
// 1 exp2, accumulate own V-slice. ~33 instrs/16 edges vs r18's 52.
// Epilogue merges over lane bits 2..5. Masked p keeps dn exact.
#define QPROC(rk, rv, vld)                                                   \
  {                                                                          \
    h2v k0 = u2h2(rk.x), k1 = u2h2(rk.y), k2 = u2h2(rk.z), k3 = u2h2(rk.w);  \
    float d = __builtin_amdgcn_fdot2(k3, q3, 0.f, false);                    \
    d = __builtin_amdgcn_fdot2(k2, q2, d, false);                            \
    d = __builtin_amdgcn_fdot2(k1, q1, d, false);                            \
    d = __builtin_amdgcn_fdot2(k0, q0, d, false);                            \
    d += DPPF(d, 0xB1);              /* xor1: quad_perm(1,0,3,2) */          \
    d += DPPF(d, 0x4E);              /* xor2: quad_perm(2,3,0,1) */          \
    float p = (vld) ? exp2f(d) : 0.f;                                        \
    dn += p;                                                                 \
    h2v v0 = u2h2(rv.x), v1 = u2h2(rv.y), v2 = u2h2(rv.z), v3 = u2h2(rv.w);  \
    a0 = fmaf(p, (float)v0[0], a0); a1 = fmaf(p, (float)v0[1], a1);          \
    a2 = fmaf(p, (float)v1[0], a2); a3 = fmaf(p, (float)v1[1], a3);          \
    a4 = fmaf(p, (float)v2[0], a4); a5 = fmaf(p, (float)v2[1], a5);          \
    a6 = fmaf(p, (float)v3[0], a6); a7 = fmaf(p, (float)v3[1], a7);          \
  }

__global__ __launch_bounds__(256) void attn_kernel(
    const short* __restrict__ Qh, const short* __restrict__ KVh,
    const int* __restrict__ offsets, const int* __restrict__ col_sorted,
    float* __restrict__ out, int n_node) {
  int head = blockIdx.x & 7;   // XCD-pinned
  int grp = blockIdx.x >> 3;
  int wv = threadIdx.x >> 6;
  int lane = threadIdx.x & 63;
  int eslot = lane >> 2;  // edge slot 0..15
  int q4 = lane & 3;      // dim slice: dims q4*8 .. q4*8+7
  int node = grp * 4 + wv;
  if (node >= n_node) return;
  int start = offsets[node], end = offsets[node + 1];

  if (end <= start) {
    if (lane < 4) {
      float* op = out + (size_t)node * HD + head * 32 + q4 * 8;
      float4 z = make_float4(0.f, 0.f, 0.f, 0.f);
      *(float4*)op = z;
      *(float4*)(op + 4) = z;
    }
    return;
  }

  // q slice (q4): 8 f16 kept PACKED (pre-scaled at GEMM)
  h2v q0, q1, q2, q3;
  {
    uint4 qr = *(const uint4*)((const char*)(Qh +
                ((size_t)head * n_node + node) * 32) + q4 * 16);
    q0 = u2h2(qr.x); q1 = u2h2(qr.y); q2 = u2h2(qr.z); q3 = u2h2(qr.w);
  }
  float dn = 0.f;
  float a0 = 0.f, a1 = 0.f, a2 = 0.f, a3 = 0.f;
  float a4 = 0.f, a5 = 0.f, a6 = 0.f, a7 = 0.f;

  const char* kvb = (const char*)KVh + (size_t)head * n_node * 128;
  unsigned int qoff = (unsigned int)q4 << 4;

  for (int base = start; base < end; base += 32) {
    int i0 = base + eslot, i1 = base + 16 + eslot;
    bool v0 = i0 < end, v1 = i1 < end;
    int c0 = col_sorted[v0 ? i0 : start];
    int c1 = col_sorted[v1 ? i1 : start];
    unsigned int b0 = ((unsigned int)c0 << 7) + qoff;
    unsigned int b1 = ((unsigned int)c1 << 7) + qoff;
    uint4 rk0 = *(const uint4*)(kvb + b0);
    uint4 rv0 = *(const uint4*)(kvb + b0 + 64);
    uint4 rk1 = *(const uint4*)(kvb + b1);
    uint4 rv1 = *(const uint4*)(kvb + b1 + 64);
    QPROC(rk0, rv0, v0);
    QPROC(rk1, rv1, v1);
  }

  // merge the 16 edge slots: xor over lane bits 2..5 (once per node)
  dn += __shfl_xor(dn, 4); dn += __shfl_xor(dn, 8);
  dn += __shfl_xor(dn, 16); dn += __shfl_xor(dn, 32);
#define MRG(x)                                                               \
  x += __shfl_xor(x, 4); x += __shfl_xor(x, 8);                              \
  x += __shfl_xor(x, 16); x += __shfl_xor(x, 32);
  MRG(a0) MRG(a1) MRG(a2) MRG(a3) MRG(a4) MRG(a5) MRG(a6) MRG(a7)

  float inv = 1.f / dn;
  if (lane < 4) {  // lane q4 holds dims q4*8..q4*8+7
    float* op = out + (size_t)node * HD + head * 32 + q4 * 8;
    float4 o0 = make_float4(a0 * inv, a1 * inv, a2 * inv, a3 * inv);
    float4 o1 = make_float4(a4 * inv, a5 * inv, a6 * inv, a7 * inv);
    *(float4*)op = o0;
    *(float4*)(op + 4) = o1;
  }
}

extern "C" void kernel_launch(void* const* d_in, const int* in_sizes, int n_in,
                              void* d_out, int out_size, void* d_ws,
                              size_t ws_size, hipStream_t stream) {
  const float* h = (const float*)d_in[0];
  const int* edge = (const int*)d_in[1];
  const float* WQ = (const float*)d_in[2];
  const float* WK = (const float*)d_in[3];
  const float* WV = (const float*)d_in[4];
  float* out = (float*)d_out;

  int n_node = in_sizes[0] / D_IN;
  int n_edge = in_sizes[1] / 2;
  const int* row = edge;
  const int* col = edge + n_edge;

  char* ws = (char*)d_ws;
  size_t off = 0;
  auto alloc = [&](size_t bytes) {
    void* p = ws + off;
    off += (bytes + 255) & ~(size_t)255;
    return p;
  };
  int nt_total = (n_node + 15) / 16;  // 3125 (50000 = 3125*16 exactly)
  short* Qh = (short*)alloc((size_t)NH * n_node * 32 * 2);
  short* KVh = (short*)alloc((size_t)NH * n_node * 64 * 2);
  short8* Bbuf = (short8*)alloc((size_t)48 * 4 * 64 * 16);
  int* col_sorted = (int*)alloc((size_t)n_edge * 4);
  int* rank = (int*)alloc((size_t)n_edge * 4);
  int* cnt = (int*)alloc((size_t)n_node * 4);
  int* offsets = (int*)alloc((size_t)(n_node + 1) * 4);
  int* bsum = (int*)alloc(256 * 4);

  hipMemsetAsync(cnt, 0, (size_t)n_node * 4, stream);

  prep_w_kernel<<<48, 256, 0, stream>>>(WQ, WK, WV, Bbuf);
  gemm_qkv_kernel<<<nt_total, 256, 0, stream>>>(h, Bbuf, Qh, KVh, nt_total,
                                                n_node);

  int nb_e = (n_edge + 255) / 256;
  rank_kernel<<<nb_e, 256, 0, stream>>>(row, n_edge, cnt, rank);

  int nb = (n_node + 255) / 256;
  scan1_kernel<<<nb, 256, 0, stream>>>(cnt, n_node, offsets, bsum);
  scan2_kernel<<<1, 256, 0, stream>>>(bsum, nb);
  scan3_kernel<<<nb, 256, 0, stream>>>(offsets, bsum, n_node, n_edge);

  scatter_kernel<<<nb_e, 256, 0, stream>>>(row, col, rank, n_edge, offsets,
                                           col_sorted);

  attn_kernel<<<((n_node + 3) / 4) * 8, 256, 0, stream>>>(
      Qh, KVh, offsets, col_sorted, out, n_node);
}